// Round 7
// baseline (246.286 us; speedup 1.0000x reference)
//
#include <hip/hip_runtime.h>

// Mixtral router aux loss:
//   loss = 0.02 * 8 * sum_e (top2_count[e]/T) * (probsum[e]/T)
// T = 4194304 tokens, E = 8 experts, fp32 logits. Memory-bound: 128 MiB read,
// floor ~19.5 us at the ~6.9 TB/s measured device ceiling (harness fills run 85-88%).
//
// SINGLE dispatch, no workspace init:
//  - per-block reduce in registers/LDS as before
//  - cross-block accumulation via fp32 atomicAdd into 17 strided ws cells
//  - arrival counter is ALSO an fp32 atomicAdd(1.0f): works for both 0xAA-poisoned
//    ws (0xAAAAAAAA as f32 = -3.03e-13, absorbed exactly by first rounding) and
//    zeroed ws. Exactly one block sees old == GRID-1 and finalizes the scalar.
//    Counts accumulate exactly in fp32 (all values integers <= 2^24).

constexpr int NE      = 8;
constexpr int T_TOK   = 4194304;
constexpr int BLOCK   = 256;
constexpr int GRID    = 1024;
constexpr int TPT     = T_TOK / (BLOCK * GRID);   // 16 tokens per thread

constexpr int WS_STRIDE = 16;                     // 64 B between cells
// cells: e*16 -> probsum[e];  (8+e)*16 -> count[e];  16*16 -> arrival counter

__global__ __launch_bounds__(BLOCK) void router_fused(const float* __restrict__ gate,
                                                      float* __restrict__ wsf,
                                                      float* __restrict__ out) {
  float ps[NE];
#pragma unroll
  for (int e = 0; e < NE; ++e) ps[e] = 0.f;
  unsigned cnt[4] = {0u, 0u, 0u, 0u};  // 16-bit fields: cnt[p] = c[2p] | c[2p+1]<<16

  const int tid = blockIdx.x * BLOCK + threadIdx.x;
  const int NT  = BLOCK * GRID;

#pragma unroll 4
  for (int j = 0; j < TPT; ++j) {
    const int tok = tid + j * NT;
    const float4* gp = reinterpret_cast<const float4*>(gate) + (size_t)tok * 2;
    const float4 a = gp[0];
    const float4 b = gp[1];
    float x[NE] = {a.x, a.y, a.z, a.w, b.x, b.y, b.z, b.w};

    // top-1 (strict > keeps lowest index on ties, matching jax.lax.top_k)
    float m1 = x[0]; int i1 = 0;
#pragma unroll
    for (int e = 1; e < NE; ++e) {
      const bool g = x[e] > m1;
      m1 = g ? x[e] : m1;
      i1 = g ? e : i1;
    }
    // top-2
    float m2 = -3.4e38f; int i2 = 0;
#pragma unroll
    for (int e = 0; e < NE; ++e) {
      const float v = (e == i1) ? -3.4e38f : x[e];
      const bool g = v > m2;
      m2 = g ? v : m2;
      i2 = g ? e : i2;
    }

    // softmax accumulate (probabilities normalized; exp via hardware v_exp)
    float p[NE];
    float s = 0.f;
#pragma unroll
    for (int e = 0; e < NE; ++e) { p[e] = __expf(x[e] - m1); s += p[e]; }
    const float r = 1.0f / s;
#pragma unroll
    for (int e = 0; e < NE; ++e) ps[e] += p[e] * r;

    // counts: statically-indexed packed adds
#pragma unroll
    for (int pq = 0; pq < 4; ++pq) {
      const unsigned lo = (unsigned)((i1 == 2 * pq)     | (i2 == 2 * pq));
      const unsigned hi = (unsigned)((i1 == 2 * pq + 1) | (i2 == 2 * pq + 1));
      cnt[pq] += lo + (hi << 16);
    }
  }

  // wave (64-lane) shuffle reduction: 12 values x 6 levels
#pragma unroll
  for (int off = 32; off > 0; off >>= 1) {
#pragma unroll
    for (int e = 0; e < NE; ++e) ps[e] += __shfl_down(ps[e], off);
#pragma unroll
    for (int pq = 0; pq < 4; ++pq)
      cnt[pq] += (unsigned)__shfl_down((int)cnt[pq], off);
  }

  // cross-wave stage in LDS
  __shared__ float    s_ps[BLOCK / 64][NE];
  __shared__ unsigned s_cnt[BLOCK / 64][4];
  const int lane = threadIdx.x & 63;
  const int wid  = threadIdx.x >> 6;
  if (lane == 0) {
#pragma unroll
    for (int e = 0; e < NE; ++e) s_ps[wid][e] = ps[e];
#pragma unroll
    for (int pq = 0; pq < 4; ++pq) s_cnt[wid][pq] = cnt[pq];
  }
  __syncthreads();

  // threads 0..7: one fp32 atomicAdd per probsum cell and per count cell
  if (threadIdx.x < NE) {
    const int e = threadIdx.x;
    float v = 0.f;
#pragma unroll
    for (int w = 0; w < BLOCK / 64; ++w) v += s_ps[w][e];
    atomicAdd(&wsf[e * WS_STRIDE], v);

    unsigned c = 0;
#pragma unroll
    for (int w = 0; w < BLOCK / 64; ++w)
      c += (s_cnt[w][e >> 1] >> ((e & 1) * 16)) & 0xFFFFu;
    atomicAdd(&wsf[(NE + e) * WS_STRIDE], (float)c);   // exact: integer <= 8192

    __threadfence();   // make this thread's data atomics visible device-wide
  }
  __syncthreads();     // all 8 fences done before the arrival ticket

  if (threadIdx.x == 0) {
    const float old = atomicAdd(&wsf[2 * NE * WS_STRIDE], 1.0f);
    if (old == (float)(GRID - 1)) {      // exactly one block: all data is in
      __threadfence();
      double acc = 0.0;
#pragma unroll
      for (int e = 0; e < NE; ++e) {
        const double p = (double)atomicAdd(&wsf[e * WS_STRIDE], 0.0f);        // coherent read
        const double c = (double)atomicAdd(&wsf[(NE + e) * WS_STRIDE], 0.0f); // coherent read
        acc += p * c;
      }
      const double T = (double)T_TOK;
      out[0] = (float)(0.02 * 8.0 * acc / (T * T));
    }
  }
}

extern "C" void kernel_launch(void* const* d_in, const int* in_sizes, int n_in,
                              void* d_out, int out_size, void* d_ws, size_t ws_size,
                              hipStream_t stream) {
  const float* gate = (const float*)d_in[0];
  float* out = (float*)d_out;
  float* wsf = (float*)d_ws;   // uses 17 cells * 64 B; poison/zero both handled exactly

  router_fused<<<GRID, BLOCK, 0, stream>>>(gate, wsf, out);
}

// Round 8
// 185.925 us; speedup vs baseline: 1.3247x; 1.3247x over previous
//
#include <hip/hip_runtime.h>

// Mixtral router aux loss:
//   loss = 0.02 * 8 * sum_e (top2_count[e]/T) * (probsum[e]/T)
// T = 4194304 tokens, E = 8 experts, fp32 logits. Memory-bound: 128 MiB read,
// floor ~19.5 us at the ~6.9 TB/s measured device ceiling.
//
// Two dispatches, no ws init, NO cross-block atomics/fences (R7 showed that
// in-kernel grid consensus costs ~90 us on 8 non-coherent XCDs):
//   router_accum:    per-block reduce -> 16-value partial per block (64 B store)
//   router_finalize: 1 wave reduces 1024 partials -> scalar

constexpr int NE      = 8;
constexpr int T_TOK   = 4194304;
constexpr int BLOCK   = 256;
constexpr int GRID    = 1024;
constexpr int TPT     = T_TOK / (BLOCK * GRID);   // 16 tokens per thread

__global__ __launch_bounds__(BLOCK) void router_accum(const float* __restrict__ gate,
                                                      float* __restrict__ part) {
  float ps[NE];
#pragma unroll
  for (int e = 0; e < NE; ++e) ps[e] = 0.f;
  unsigned cnt[4] = {0u, 0u, 0u, 0u};  // 16-bit fields: cnt[p] = c[2p] | c[2p+1]<<16

  const int tid = blockIdx.x * BLOCK + threadIdx.x;
  const int NT  = BLOCK * GRID;

#pragma unroll 4
  for (int j = 0; j < TPT; ++j) {
    const int tok = tid + j * NT;
    const float4* gp = reinterpret_cast<const float4*>(gate) + (size_t)tok * 2;
    const float4 a = gp[0];
    const float4 b = gp[1];
    float x[NE] = {a.x, a.y, a.z, a.w, b.x, b.y, b.z, b.w};

    // top-1 (strict > keeps lowest index on ties, matching jax.lax.top_k)
    float m1 = x[0]; int i1 = 0;
#pragma unroll
    for (int e = 1; e < NE; ++e) {
      const bool g = x[e] > m1;
      m1 = g ? x[e] : m1;
      i1 = g ? e : i1;
    }
    // top-2
    float m2 = -3.4e38f; int i2 = 0;
#pragma unroll
    for (int e = 0; e < NE; ++e) {
      const float v = (e == i1) ? -3.4e38f : x[e];
      const bool g = v > m2;
      m2 = g ? v : m2;
      i2 = g ? e : i2;
    }

    // softmax accumulate (probabilities normalized; exp via hardware v_exp)
    float p[NE];
    float s = 0.f;
#pragma unroll
    for (int e = 0; e < NE; ++e) { p[e] = __expf(x[e] - m1); s += p[e]; }
    const float r = 1.0f / s;
#pragma unroll
    for (int e = 0; e < NE; ++e) ps[e] += p[e] * r;

    // counts: statically-indexed packed adds
#pragma unroll
    for (int pq = 0; pq < 4; ++pq) {
      const unsigned lo = (unsigned)((i1 == 2 * pq)     | (i2 == 2 * pq));
      const unsigned hi = (unsigned)((i1 == 2 * pq + 1) | (i2 == 2 * pq + 1));
      cnt[pq] += lo + (hi << 16);
    }
  }

  // wave (64-lane) shuffle reduction: 12 values x 6 levels
#pragma unroll
  for (int off = 32; off > 0; off >>= 1) {
#pragma unroll
    for (int e = 0; e < NE; ++e) ps[e] += __shfl_down(ps[e], off);
#pragma unroll
    for (int pq = 0; pq < 4; ++pq)
      cnt[pq] += (unsigned)__shfl_down((int)cnt[pq], off);
  }

  // cross-wave stage in LDS, then write this block's partial (16 values, 64 B)
  __shared__ float    s_ps[BLOCK / 64][NE];
  __shared__ unsigned s_cnt[BLOCK / 64][4];
  const int lane = threadIdx.x & 63;
  const int wid  = threadIdx.x >> 6;
  if (lane == 0) {
#pragma unroll
    for (int e = 0; e < NE; ++e) s_ps[wid][e] = ps[e];
#pragma unroll
    for (int pq = 0; pq < 4; ++pq) s_cnt[wid][pq] = cnt[pq];
  }
  __syncthreads();
  if (threadIdx.x < NE) {
    const int e = threadIdx.x;
    float v = 0.f;
#pragma unroll
    for (int w = 0; w < BLOCK / 64; ++w) v += s_ps[w][e];
    part[blockIdx.x * 16 + e] = v;

    unsigned c = 0;
#pragma unroll
    for (int w = 0; w < BLOCK / 64; ++w)
      c += (s_cnt[w][e >> 1] >> ((e & 1) * 16)) & 0xFFFFu;
    reinterpret_cast<unsigned*>(part)[blockIdx.x * 16 + NE + e] = c;
  }
}

// single wave: no LDS, no __syncthreads
__global__ __launch_bounds__(64) void router_finalize(const float* __restrict__ part,
                                                      float* __restrict__ out) {
  float    ps[NE];
  unsigned cnt[NE];
#pragma unroll
  for (int e = 0; e < NE; ++e) { ps[e] = 0.f; cnt[e] = 0u; }

#pragma unroll 4
  for (int b = threadIdx.x; b < GRID; b += 64) {
    const float4* f4 = reinterpret_cast<const float4*>(part) + (size_t)b * 4;
    const float4 a = f4[0];
    const float4 c = f4[1];
    const uint4  u0 = *reinterpret_cast<const uint4*>(f4 + 2);
    const uint4  u1 = *reinterpret_cast<const uint4*>(f4 + 3);
    ps[0] += a.x; ps[1] += a.y; ps[2] += a.z; ps[3] += a.w;
    ps[4] += c.x; ps[5] += c.y; ps[6] += c.z; ps[7] += c.w;
    cnt[0] += u0.x; cnt[1] += u0.y; cnt[2] += u0.z; cnt[3] += u0.w;
    cnt[4] += u1.x; cnt[5] += u1.y; cnt[6] += u1.z; cnt[7] += u1.w;
  }

#pragma unroll
  for (int off = 32; off > 0; off >>= 1) {
#pragma unroll
    for (int e = 0; e < NE; ++e) {
      ps[e]  += __shfl_down(ps[e], off);
      cnt[e] += (unsigned)__shfl_down((int)cnt[e], off);
    }
  }

  if (threadIdx.x == 0) {
    double acc = 0.0;
#pragma unroll
    for (int e = 0; e < NE; ++e) acc += (double)ps[e] * (double)cnt[e];
    const double T = (double)T_TOK;
    out[0] = (float)(0.02 * 8.0 * acc / (T * T));
  }
}

extern "C" void kernel_launch(void* const* d_in, const int* in_sizes, int n_in,
                              void* d_out, int out_size, void* d_ws, size_t ws_size,
                              hipStream_t stream) {
  const float* gate = (const float*)d_in[0];
  float* out  = (float*)d_out;
  float* part = (float*)d_ws;   // 1024 blocks * 16 floats = 64 KB, fully written before read

  router_accum<<<GRID, BLOCK, 0, stream>>>(gate, part);
  router_finalize<<<1, 64, 0, stream>>>(part, out);
}